// Round 10
// baseline (376.641 us; speedup 1.0000x reference)
//
#include <hip/hip_runtime.h>
#include <hip/hip_fp16.h>

#define M_TOK 16384
#define H_DIM 1024
#define F_DIM 4096

typedef __attribute__((ext_vector_type(4))) int int4v;
typedef __attribute__((ext_vector_type(16))) int int16v;
typedef __attribute__((ext_vector_type(4))) float f32x4;

// ---------------- workspace layout (bytes) ----------------
static const size_t OFF_H2    = 0;                       // fp16 [M,F]  134,217,728
static const size_t OFF_RS2   = OFF_H2   + 134217728ULL; // f32 [M] (reuses old q2 slot)
static const size_t OFF_XQ    = OFF_RS2  + 67108864ULL;  // int8 [M,H]   16,777,216
static const size_t OFF_WQU   = OFF_XQ   + 16777216ULL;  // int8 [F,H]    4,194,304
static const size_t OFF_WQD   = OFF_WQU  + 4194304ULL;   // int8 [H,F]    4,194,304
static const size_t OFF_DQX   = OFF_WQD  + 4194304ULL;   // f32 [M]          65,536
static const size_t OFF_DQ2   = OFF_DQX  + 65536ULL;     // f32 [M]          65,536
static const size_t OFF_PMAX  = OFF_DQ2  + 65536ULL;     // f32 [64,M]    4,194,304
static const size_t OFF_WPART = OFF_PMAX + 4194304ULL;   // f32 [2048]        8,192
static const size_t OFF_WSC   = OFF_WPART+ 8192ULL;      // f32 [4]
static const size_t WS_NEEDED = OFF_WSC  + 16ULL;

__device__ __forceinline__ void ldg_lds16(const void* g, void* l) {
  __builtin_amdgcn_global_load_lds(
      (const __attribute__((address_space(1))) void*)g,
      (__attribute__((address_space(3))) void*)l, 16, 0, 0);
}

// 32-byte global load as 2x dwordx4 via asm: pinned program order so the vmcnt
// FIFO accounting below stays exact (compiler cannot sink/hoist these).
__device__ __forceinline__ void gload32(const void* p, f32x4& a, f32x4& b) {
  asm volatile("global_load_dwordx4 %0, %2, off\n\t"
               "global_load_dwordx4 %1, %2, off offset:16"
               : "=&v"(a), "=&v"(b) : "v"(p) : "memory");
}

// ---------------- K1: |w| partial sums (deterministic) ----------------
__global__ __launch_bounds__(256) void k_wabs(const float* __restrict__ wu,
                                              const float* __restrict__ wd,
                                              float* __restrict__ part) {
  const int b = blockIdx.x;                 // 0..2047 (1024 per tensor)
  const float* w = (b < 1024) ? wu : wd;
  const int cb = b & 1023;
  const size_t base = (size_t)cb * 4096 + threadIdx.x * 4;
  float s = 0.0f;
#pragma unroll
  for (int it = 0; it < 4; ++it) {
    const float4 v = *(const float4*)(w + base + it * 1024);
    s += fabsf(v.x) + fabsf(v.y) + fabsf(v.z) + fabsf(v.w);
  }
#pragma unroll
  for (int sh = 32; sh; sh >>= 1) s += __shfl_xor(s, sh, 64);
  __shared__ float red[4];
  if ((threadIdx.x & 63) == 0) red[threadIdx.x >> 6] = s;
  __syncthreads();
  if (threadIdx.x == 0) part[b] = red[0] + red[1] + red[2] + red[3];
}

// ---------------- K2: finalize per-tensor scale ----------------
__global__ __launch_bounds__(256) void k_wscale(const float* __restrict__ part,
                                                float* __restrict__ wsc) {
  const int b = blockIdx.x;                 // 0: w_up, 1: w_down
  const float* p = part + b * 1024;
  float s = p[threadIdx.x] + p[threadIdx.x + 256] + p[threadIdx.x + 512] + p[threadIdx.x + 768];
#pragma unroll
  for (int sh = 32; sh; sh >>= 1) s += __shfl_xor(s, sh, 64);
  __shared__ float red[4];
  if ((threadIdx.x & 63) == 0) red[threadIdx.x >> 6] = s;
  __syncthreads();
  if (threadIdx.x == 0) {
    const float mean = (red[0] + red[1] + red[2] + red[3]) * (1.0f / 4194304.0f);
    const float c = fmaxf(mean, 1e-5f);
    wsc[b * 2]     = c;         // dequant factor (1/scale)
    wsc[b * 2 + 1] = 1.0f / c;  // scale
  }
}

// ---------------- K3: ternary-quantize both weights ----------------
__global__ __launch_bounds__(256) void k_wquant(const float* __restrict__ wu,
                                                const float* __restrict__ wd,
                                                char* __restrict__ qu,
                                                char* __restrict__ qd,
                                                const float* __restrict__ wsc) {
  const size_t t = (size_t)blockIdx.x * 256 + threadIdx.x;  // 0..2097151
  const float* w; char* q; float scale; size_t i;
  if (t < 1048576) { w = wu; q = qu; scale = wsc[1]; i = t * 4; }
  else             { w = wd; q = qd; scale = wsc[3]; i = (t - 1048576) * 4; }
  const float4 v = *(const float4*)(w + i);
  const int a = (int)rintf(fminf(fmaxf(v.x * scale, -1.0f), 1.0f));
  const int b = (int)rintf(fminf(fmaxf(v.y * scale, -1.0f), 1.0f));
  const int c = (int)rintf(fminf(fmaxf(v.z * scale, -1.0f), 1.0f));
  const int d = (int)rintf(fminf(fmaxf(v.w * scale, -1.0f), 1.0f));
  *(unsigned*)(q + i) = (a & 255) | ((b & 255) << 8) | ((c & 255) << 16) | ((d & 255) << 24);
}

// ---------------- K4: fused RMSNorm + act_quant ----------------
__global__ __launch_bounds__(256) void k_rmsnorm_quant(const float* __restrict__ x,
                                                       const float* __restrict__ nw,
                                                       char* __restrict__ xq,
                                                       float* __restrict__ dqx) {
  const int row = blockIdx.x;
  const int t = threadIdx.x;
  const float4 v = *(const float4*)(x + (size_t)row * H_DIM + t * 4);
  float ss = v.x * v.x + v.y * v.y + v.z * v.z + v.w * v.w;
#pragma unroll
  for (int sh = 32; sh; sh >>= 1) ss += __shfl_xor(ss, sh, 64);
  __shared__ float red[4];
  __shared__ float redm[4];
  if ((t & 63) == 0) red[t >> 6] = ss;
  __syncthreads();
  ss = red[0] + red[1] + red[2] + red[3];
  const float rinv = 1.0f / sqrtf(ss * (1.0f / 1024.0f) + 1e-6f);
  const float4 w4 = *(const float4*)(nw + t * 4);
  float4 n;
  n.x = v.x * rinv * w4.x;  n.y = v.y * rinv * w4.y;
  n.z = v.z * rinv * w4.z;  n.w = v.w * rinv * w4.w;
  float am = fmaxf(fmaxf(fabsf(n.x), fabsf(n.y)), fmaxf(fabsf(n.z), fabsf(n.w)));
#pragma unroll
  for (int sh = 32; sh; sh >>= 1) am = fmaxf(am, __shfl_xor(am, sh, 64));
  if ((t & 63) == 0) redm[t >> 6] = am;
  __syncthreads();
  am = fmaxf(fmaxf(redm[0], redm[1]), fmaxf(redm[2], redm[3]));
  am = fmaxf(am, 1e-5f);
  const float scale = 127.0f / am;
  const int qa = (int)rintf(fminf(fmaxf(n.x * scale, -128.0f), 127.0f));
  const int qb = (int)rintf(fminf(fmaxf(n.y * scale, -128.0f), 127.0f));
  const int qc = (int)rintf(fminf(fmaxf(n.z * scale, -128.0f), 127.0f));
  const int qd = (int)rintf(fminf(fmaxf(n.w * scale, -128.0f), 127.0f));
  *(unsigned*)(xq + (size_t)row * H_DIM + t * 4) =
      (qa & 255) | ((qb & 255) << 8) | ((qc & 255) << 16) | ((qd & 255) << 24);
  if (t == 0) dqx[row] = am * (1.0f / 127.0f);
}

// ---------------- shared int8 GEMM core: 256x256, BK=128, 32x32x32 MFMA ----------------
// Schedule/staging/LDS layout = round-5 verbatim (best measured: 86.7us, 0 conflicts).
// MFMA shape change only: v_mfma_i32_32x32x32_i8 — half the instruction count
// (32 vs 64 per wave per K-tile), +12% rate ceiling (4404 vs 3944 TOPS, m55),
// uniform 6-8 ds_reads/phase. Fragment maps (extrapolating the working 16x16x64
// pattern lane=row+R*k_chunk): A/B lane l holds row/col (l&31), 16B k-chunk (l>>5).
// K-tile = 128B -> 4 ks-slices of 32B; slice ks, chunk kh -> global seg ks*2+kh,
// stored at slot ((ks*2+kh) ^ (row&7)). C/D: col=lane&31,
// row=(reg&3)+8*(reg>>2)+4*(lane>>5) [m74/m101, dtype-independent m121-128].
// Per wave output 128x64 = acc[4][2] 32x32 tiles (128 VGPR, same as before).
// Phase->row mapping preserves r5's publish schedule: P0/P2 read wave-half rows
// 0-63 (quarters staged P2, published end-P3 prior); P1/P3 read rows 64-127
// (staged P3, published end-P0 current). Int accumulation -> bit-identical C.
#define MFMA32(i, j, av, bv) \
  acc[i][j] = __builtin_amdgcn_mfma_i32_32x32x32_i8(av, bv, acc[i][j], 0, 0, 0)

#define MFMA8(i0, i1) \
  __builtin_amdgcn_s_setprio(1); \
  MFMA32(i0, 0, aA, b00); MFMA32(i0, 1, aA, b10); \
  MFMA32(i1, 0, aB, b00); MFMA32(i1, 1, aB, b10); \
  MFMA32(i0, 0, aC, b01); MFMA32(i0, 1, aC, b11); \
  MFMA32(i1, 0, aD, b01); MFMA32(i1, 1, aD, b11); \
  __builtin_amdgcn_s_setprio(0)

template <int LDA_, int LDB_, int KT>
__device__ __forceinline__ void gemm_core4p(const char* __restrict__ A,
                                            const char* __restrict__ B,
                                            int mBase, int nBase,
                                            char* __restrict__ smem,
                                            int16v acc[4][2]) {
  const int t = threadIdx.x;          // 0..511
  const int lane = t & 63;
  const int w = t >> 6;               // wave 0..7
  const int wm = w & 1;               // rows wm*128
  const int wn = w >> 1;              // cols wn*64
  const int sRow = t >> 3;            // 0..63
  const int sSeg = (t & 7) ^ (sRow & 7);
  const char* Ag = A + (size_t)(mBase + sRow) * LDA_ + sSeg * 16;
  const char* Bg = B + (size_t)(nBase + sRow) * LDB_ + sSeg * 16;
  const int l31 = lane & 31;
  const int kh  = lane >> 5;          // 16B k-chunk within 32B slice
  const int sw  = l31 & 7;
  const int so0 = (((0 * 2 + kh) ^ sw) << 4);
  const int so1 = (((1 * 2 + kh) ^ sw) << 4);
  const int so2 = (((2 * 2 + kh) ^ sw) << 4);
  const int so3 = (((3 * 2 + kh) ^ sw) << 4);
  const int aOff = (wm * 128 + l31) * 128;   // A row base (bytes)
  const int bOff = (wn * 64 + l31) * 128;    // B row base (bytes)
  const int dst = t << 4;

#define STG_A(Q, KTI, BUFO) \
  ldg_lds16(Ag + (size_t)((Q) * 64) * LDA_ + (size_t)(KTI) * 128, \
            smem + (BUFO) + (Q) * 8192 + dst)
#define STG_B(Q, KTI, BUFO) \
  ldg_lds16(Bg + (size_t)((Q) * 64) * LDB_ + (size_t)(KTI) * 128, \
            smem + (BUFO) + 32768 + (Q) * 8192 + dst)

  STG_B(0, 0, 0); STG_B(1, 0, 0); STG_B(2, 0, 0); STG_B(3, 0, 0);
  STG_A(0, 0, 0); STG_A(2, 0, 0); STG_A(1, 0, 0); STG_A(3, 0, 0);
  asm volatile("s_waitcnt vmcnt(2)\n\ts_barrier" ::: "memory");

  int cur = 0;
  for (int kt = 0; kt < KT; ++kt) {
    const int nxt = cur ^ 65536;
    const char* Ab = smem + cur;
    const char* Bb = smem + cur + 32768;
    int4v aA, aB, aC, aD, b00, b10, b01, b11;
    // ---- P0: rows 0..63 of wave half, ks0+ks1 ----
    aA  = *(const int4v*)(Ab + aOff +    0 + so0);
    aB  = *(const int4v*)(Ab + aOff + 4096 + so0);
    aC  = *(const int4v*)(Ab + aOff +    0 + so1);
    aD  = *(const int4v*)(Ab + aOff + 4096 + so1);
    b00 = *(const int4v*)(Bb + bOff +    0 + so0);
    b10 = *(const int4v*)(Bb + bOff + 4096 + so0);
    b01 = *(const int4v*)(Bb + bOff +    0 + so1);
    b11 = *(const int4v*)(Bb + bOff + 4096 + so1);
    if (kt + 1 < KT) { STG_B(0, kt + 1, nxt); STG_B(1, kt + 1, nxt); }
    MFMA8(0, 1);
    if (kt + 1 < KT) { asm volatile("s_waitcnt vmcnt(2)\n\ts_barrier" ::: "memory"); }
    else             { asm volatile("s_waitcnt vmcnt(0)\n\ts_barrier" ::: "memory"); }
    // ---- P1: rows 64..127, ks0+ks1 (b regs reused) ----
    aA  = *(const int4v*)(Ab + aOff +  8192 + so0);
    aB  = *(const int4v*)(Ab + aOff + 12288 + so0);
    aC  = *(const int4v*)(Ab + aOff +  8192 + so1);
    aD  = *(const int4v*)(Ab + aOff + 12288 + so1);
    if (kt + 1 < KT) { STG_B(2, kt + 1, nxt); STG_B(3, kt + 1, nxt); }
    MFMA8(2, 3);
    // ---- P2: rows 0..63, ks2+ks3 ----
    aA  = *(const int4v*)(Ab + aOff +    0 + so2);
    aB  = *(const int4v*)(Ab + aOff + 4096 + so2);
    aC  = *(const int4v*)(Ab + aOff +    0 + so3);
    aD  = *(const int4v*)(Ab + aOff + 4096 + so3);
    b00 = *(const int4v*)(Bb + bOff +    0 + so2);
    b10 = *(const int4v*)(Bb + bOff + 4096 + so2);
    b01 = *(const int4v*)(Bb + bOff +    0 + so3);
    b11 = *(const int4v*)(Bb + bOff + 4096 + so3);
    if (kt + 1 < KT) { STG_A(0, kt + 1, nxt); STG_A(2, kt + 1, nxt); }
    MFMA8(0, 1);
    // ---- P3: rows 64..127, ks2+ks3 ----
    aA  = *(const int4v*)(Ab + aOff +  8192 + so2);
    aB  = *(const int4v*)(Ab + aOff + 12288 + so2);
    aC  = *(const int4v*)(Ab + aOff +  8192 + so3);
    aD  = *(const int4v*)(Ab + aOff + 12288 + so3);
    if (kt + 1 < KT) { STG_A(1, kt + 1, nxt); STG_A(3, kt + 1, nxt); }
    MFMA8(2, 3);
    asm volatile("s_waitcnt vmcnt(2)\n\ts_barrier" ::: "memory");
    cur = nxt;
  }
#undef STG_A
#undef STG_B
}

// ---------------- K5: GEMM1 + relu^2 -> h2(fp16) + row-max partials ----------------
__global__ __launch_bounds__(512, 2) void k_gemm1(const char* __restrict__ xq,
                                                  const char* __restrict__ wq,
                                                  const float* __restrict__ wsc,
                                                  const float* __restrict__ dqx,
                                                  __half* __restrict__ h2,
                                                  float* __restrict__ pmax) {
  __shared__ char smem[131072];
  int16v acc[4][2];
  const int16v zz = {0,0,0,0,0,0,0,0,0,0,0,0,0,0,0,0};
#pragma unroll
  for (int i = 0; i < 4; ++i)
#pragma unroll
    for (int j = 0; j < 2; ++j) acc[i][j] = zz;
  const int mBase = blockIdx.x * 256;
  const int nBase = blockIdx.y * 256;
  gemm_core4p<H_DIM, H_DIM, 8>(xq, wq, mBase, nBase, smem, acc);

  const int t = threadIdx.x;
  const int lane = t & 63;
  const int w = t >> 6;
  const int wm = w & 1;
  const int wn = w >> 1;
  const int l31 = lane & 31;
  const int kh  = lane >> 5;
  const float dqw = wsc[0];
#pragma unroll
  for (int i = 0; i < 4; ++i) {
    float rmax[16];
#pragma unroll
    for (int r = 0; r < 16; ++r) rmax[r] = 0.0f;
#pragma unroll
    for (int j = 0; j < 2; ++j) {
      const int col = nBase + wn * 64 + j * 32 + l31;
#pragma unroll
      for (int rg = 0; rg < 4; ++rg) {
        const int rb = mBase + wm * 128 + i * 32 + rg * 8 + kh * 4;
        const float4 dq4 = *(const float4*)(dqx + rb);
        const float* dqp = (const float*)&dq4;
#pragma unroll
        for (int rr = 0; rr < 4; ++rr) {
          float v = (float)acc[i][j][rg * 4 + rr] * dqp[rr] * dqw;
          v = fmaxf(v, 0.0f);
          v = v * v;
          const __half h = __float2half(v);
          h2[(size_t)(rb + rr) * F_DIM + col] = h;
          rmax[rg * 4 + rr] = fmaxf(rmax[rg * 4 + rr], __half2float(h));
        }
      }
    }
    // reduce over 32-lane halves (cols); rows differ between halves (kh)
#pragma unroll
    for (int s = 1; s < 32; s <<= 1) {
#pragma unroll
      for (int r = 0; r < 16; ++r) rmax[r] = fmaxf(rmax[r], __shfl_xor(rmax[r], s, 64));
    }
    if (l31 == 0) {
      const int nb2 = blockIdx.y * 4 + wn;   // 64-col group
#pragma unroll
      for (int rg = 0; rg < 4; ++rg) {
        const int rb = mBase + wm * 128 + i * 32 + rg * 8 + kh * 4;
#pragma unroll
        for (int rr = 0; rr < 4; ++rr)
          pmax[(size_t)nb2 * M_TOK + rb + rr] = rmax[rg * 4 + rr];
      }
    }
  }
}

// ---------------- K5b: per-row scale from pmax ----------------
__global__ __launch_bounds__(256) void k_rowscale(const float* __restrict__ pmax,
                                                  float* __restrict__ dq2,
                                                  float* __restrict__ rs2) {
  const int row = blockIdx.x * 256 + threadIdx.x;
  float m = 0.0f;
#pragma unroll
  for (int p = 0; p < 64; ++p) m = fmaxf(m, pmax[(size_t)p * M_TOK + row]);
  m = fmaxf(m, 1e-5f);
  dq2[row] = m * (1.0f / 127.0f);
  rs2[row] = 127.0f / m;
}

// quantize 16 fp16 (2 f32x4 raw bits) -> 16 int8, identical math to old k_quant2:
// q = rint(min(v*s, 127)), v >= 0 (relu^2 output).
__device__ __forceinline__ void cvt_write_q(const f32x4& va, const f32x4& vb,
                                            float s, char* d) {
  union { f32x4 f[2]; __half2 h[8]; } u;
  u.f[0] = va; u.f[1] = vb;
  unsigned o[4];
#pragma unroll
  for (int p = 0; p < 4; ++p) {
    const float f0 = __low2float(u.h[2 * p]);
    const float f1 = __high2float(u.h[2 * p]);
    const float f2 = __low2float(u.h[2 * p + 1]);
    const float f3 = __high2float(u.h[2 * p + 1]);
    const int q0 = (int)rintf(fminf(f0 * s, 127.0f));
    const int q1 = (int)rintf(fminf(f1 * s, 127.0f));
    const int q2 = (int)rintf(fminf(f2 * s, 127.0f));
    const int q3 = (int)rintf(fminf(f3 * s, 127.0f));
    o[p] = (q0 & 255) | ((q1 & 255) << 8) | ((q2 & 255) << 16) | ((q3 & 255) << 24);
  }
  *(uint4*)d = make_uint4(o[0], o[1], o[2], o[3]);
}

// ---------------- gemm2 core: fused act-quant of A, 32x32x32 MFMA ----------------
// Staging/cvt/vmcnt structure = round-9 verbatim (passed, audited); frag/MFMA part
// changed to the 32x32 mapping exactly as in gemm_core4p. Single barrier/tile
// publishes ALL of tile kt+1 (ds_writes via lgkm(0), B-DMA via vmcnt(4)) -> every
// phase may read any row of buf[cur].
template <int KT>
__device__ __forceinline__ void gemm2_core(const __half* __restrict__ H,
                                           const char* __restrict__ B,
                                           const float* __restrict__ rs2,
                                           int mBase, int nBase,
                                           char* __restrict__ smem,
                                           int16v acc[4][2]) {
  const int t = threadIdx.x;
  const int lane = t & 63;
  const int w = t >> 6;
  const int wm = w & 1;
  const int wn = w >> 1;
  const int sRow = t >> 3;            // 0..63
  const int sSeg = (t & 7) ^ (sRow & 7);
  const __half* Hg = H + (size_t)(mBase + sRow) * F_DIM + sSeg * 16;  // half units
  const char*   Bg = B + (size_t)(nBase + sRow) * F_DIM + sSeg * 16;
  const int l31 = lane & 31;
  const int kh  = lane >> 5;
  const int sw  = l31 & 7;
  const int so0 = (((0 * 2 + kh) ^ sw) << 4);
  const int so1 = (((1 * 2 + kh) ^ sw) << 4);
  const int so2 = (((2 * 2 + kh) ^ sw) << 4);
  const int so3 = (((3 * 2 + kh) ^ sw) << 4);
  const int aOff = (wm * 128 + l31) * 128;
  const int bOff = (wn * 64 + l31) * 128;
  const int dst = t << 4;

  // per-quarter row scales (rows invariant over kt) — load then drain FIFO clean
  float rs[4];
#pragma unroll
  for (int Q = 0; Q < 4; ++Q) rs[Q] = rs2[mBase + Q * 64 + sRow];
  asm volatile("s_waitcnt vmcnt(0)" ::: "memory");
  __builtin_amdgcn_sched_barrier(0);

#define STG_B2(Q, KTI, BUFO) \
  ldg_lds16(Bg + (size_t)((Q) * 64) * F_DIM + (size_t)(KTI) * 128, \
            smem + (BUFO) + 32768 + (Q) * 8192 + dst)
#define GLD_A(arr, i0, Q, KTI) \
  gload32(Hg + (size_t)(Q) * 64 * F_DIM + (size_t)(KTI) * 128, arr[i0], arr[i0 + 1])

  f32x4 a01[4];  // quarters 0,1 of next tile (issued P3, consumed P2)
  f32x4 a23[4];  // quarters 2,3 of next tile (issued P0, consumed P3)

  // prologue: tile0 A (8 loads) + tile0 B (4 DMA); land A; convert;
  // then issue tile1-q01 into a01 (prior a01 loads retired -> no WAW, no copy).
  GLD_A(a01, 0, 0, 0); GLD_A(a01, 2, 1, 0);
  GLD_A(a23, 0, 2, 0); GLD_A(a23, 2, 3, 0);
  STG_B2(0, 0, 0); STG_B2(1, 0, 0); STG_B2(2, 0, 0); STG_B2(3, 0, 0);
  asm volatile("s_waitcnt vmcnt(4)" ::: "memory");   // tile0 A landed; B(4) in flight
  __builtin_amdgcn_sched_barrier(0);
  cvt_write_q(a01[0], a01[1], rs[0], smem + 0 * 8192 + dst);
  cvt_write_q(a01[2], a01[3], rs[1], smem + 1 * 8192 + dst);
  cvt_write_q(a23[0], a23[1], rs[2], smem + 2 * 8192 + dst);
  cvt_write_q(a23[2], a23[3], rs[3], smem + 3 * 8192 + dst);
  GLD_A(a01, 0, 0, 1); GLD_A(a01, 2, 1, 1);          // tile1 q01
  asm volatile("s_waitcnt lgkmcnt(0)" ::: "memory"); // own ds_writes drained
  // publish tile0: B(0) landed (newer = A-q01(1) = 4 stays in flight)
  asm volatile("s_waitcnt vmcnt(4)\n\ts_barrier" ::: "memory");

  int cur = 0;
  for (int kt = 0; kt < KT; ++kt) {
    const int nxt = cur ^ 65536;
    const char* Ab = smem + cur;
    const char* Bb = smem + cur + 32768;
    int4v aA, aB, aC, aD, b00, b10, b01, b11;
    // ---- P0: rows 0..63, ks0+ks1 ----
    aA  = *(const int4v*)(Ab + aOff +    0 + so0);
    aB  = *(const int4v*)(Ab + aOff + 4096 + so0);
    aC  = *(const int4v*)(Ab + aOff +    0 + so1);
    aD  = *(const int4v*)(Ab + aOff + 4096 + so1);
    b00 = *(const int4v*)(Bb + bOff +    0 + so0);
    b10 = *(const int4v*)(Bb + bOff + 4096 + so0);
    b01 = *(const int4v*)(Bb + bOff +    0 + so1);
    b11 = *(const int4v*)(Bb + bOff + 4096 + so1);
    if (kt + 1 < KT) {
      STG_B2(0, kt + 1, nxt); STG_B2(1, kt + 1, nxt);
      GLD_A(a23, 0, 2, kt + 1); GLD_A(a23, 2, 3, kt + 1);
    }
    MFMA8(0, 1);
    // ---- P1: rows 64..127, ks0+ks1 ----
    aA  = *(const int4v*)(Ab + aOff +  8192 + so0);
    aB  = *(const int4v*)(Ab + aOff + 12288 + so0);
    aC  = *(const int4v*)(Ab + aOff +  8192 + so1);
    aD  = *(const int4v*)(Ab + aOff + 12288 + so1);
    if (kt + 1 < KT) { STG_B2(2, kt + 1, nxt); STG_B2(3, kt + 1, nxt); }
    MFMA8(2, 3);
    // ---- P2: rows 0..63, ks2+ks3 ----
    aA  = *(const int4v*)(Ab + aOff +    0 + so2);
    aB  = *(const int4v*)(Ab + aOff + 4096 + so2);
    aC  = *(const int4v*)(Ab + aOff +    0 + so3);
    aD  = *(const int4v*)(Ab + aOff + 4096 + so3);
    b00 = *(const int4v*)(Bb + bOff +    0 + so2);
    b10 = *(const int4v*)(Bb + bOff + 4096 + so2);
    b01 = *(const int4v*)(Bb + bOff +    0 + so3);
    b11 = *(const int4v*)(Bb + bOff + 4096 + so3);
    if (kt + 1 < KT) {
      // A-q01(kt+1) landed: newer = B01(2)+A-q23(4)+B23(2) = 8
      asm volatile("s_waitcnt vmcnt(8)" ::: "memory");
      __builtin_amdgcn_sched_barrier(0);
      cvt_write_q(a01[0], a01[1], rs[0], smem + nxt + 0 * 8192 + dst);
      cvt_write_q(a01[2], a01[3], rs[1], smem + nxt + 1 * 8192 + dst);
    }
    MFMA8(0, 1);
    // ---- P3: rows 64..127, ks2+ks3 ----
    aA  = *(const int4v*)(Ab + aOff +  8192 + so2);
    aB  = *(const int4v*)(Ab + aOff + 12288 + so2);
    aC  = *(const int4v*)(Ab + aOff +  8192 + so3);
    aD  = *(const int4v*)(Ab + aOff + 12288 + so3);
    if (kt + 1 < KT) {
      // A-q23(kt+1) landed: newer = B23(2)
      asm volatile("s_waitcnt vmcnt(2)" ::: "memory");
      __builtin_amdgcn_sched_barrier(0);
      cvt_write_q(a23[0], a23[1], rs[2], smem + nxt + 2 * 8192 + dst);
      cvt_write_q(a23[2], a23[3], rs[3], smem + nxt + 3 * 8192 + dst);
    }
    if (kt + 2 < KT) { GLD_A(a01, 0, 0, kt + 2); GLD_A(a01, 2, 1, kt + 2); }
    MFMA8(2, 3);
    if (kt + 1 < KT) {
      asm volatile("s_waitcnt lgkmcnt(0)" ::: "memory");   // ds_writes visible
      if (kt + 2 < KT) { asm volatile("s_waitcnt vmcnt(4)\n\ts_barrier" ::: "memory"); }
      else             { asm volatile("s_waitcnt vmcnt(0)\n\ts_barrier" ::: "memory"); }
    }
    cur = nxt;
  }
#undef STG_B2
#undef GLD_A
}

// ---------------- K6: GEMM2 (fused act-quant) + dequant + residual ----------------
__global__ __launch_bounds__(512, 2) void k_gemm2(const __half* __restrict__ h2,
                                                  const char* __restrict__ wq,
                                                  const float* __restrict__ wsc,
                                                  const float* __restrict__ dq2,
                                                  const float* __restrict__ rs2,
                                                  const float* __restrict__ x,
                                                  float* __restrict__ out) {
  __shared__ char smem[131072];
  int16v acc[4][2];
  const int16v zz = {0,0,0,0,0,0,0,0,0,0,0,0,0,0,0,0};
#pragma unroll
  for (int i = 0; i < 4; ++i)
#pragma unroll
    for (int j = 0; j < 2; ++j) acc[i][j] = zz;
  const int mBase = blockIdx.x * 256;
  const int nBase = blockIdx.y * 256;
  gemm2_core<32>(h2, wq, rs2, mBase, nBase, smem, acc);

  const int t = threadIdx.x;
  const int lane = t & 63;
  const int w = t >> 6;
  const int wm = w & 1;
  const int wn = w >> 1;
  const int l31 = lane & 31;
  const int kh  = lane >> 5;
  const float dqw = wsc[2];
#pragma unroll
  for (int i = 0; i < 4; ++i) {
#pragma unroll
    for (int j = 0; j < 2; ++j) {
      const int col = nBase + wn * 64 + j * 32 + l31;
#pragma unroll
      for (int rg = 0; rg < 4; ++rg) {
        const int rb = mBase + wm * 128 + i * 32 + rg * 8 + kh * 4;
        const float4 dq4 = *(const float4*)(dq2 + rb);
        const float* dqp = (const float*)&dq4;
#pragma unroll
        for (int rr = 0; rr < 4; ++rr) {
          const size_t idx = (size_t)(rb + rr) * H_DIM + col;
          out[idx] = (float)acc[i][j][rg * 4 + rr] * dqp[rr] * dqw + x[idx];
        }
      }
    }
  }
}

extern "C" void kernel_launch(void* const* d_in, const int* in_sizes, int n_in,
                              void* d_out, int out_size, void* d_ws, size_t ws_size,
                              hipStream_t stream) {
  const float* x  = (const float*)d_in[0];
  const float* nw = (const float*)d_in[1];
  const float* wu = (const float*)d_in[2];
  const float* wd = (const float*)d_in[3];
  float* out = (float*)d_out;
  char* ws = (char*)d_ws;
  if (ws_size < WS_NEEDED) return;  // workspace too small: leave output poisoned (diagnostic)

  __half* h2     = (__half*)(ws + OFF_H2);
  float* rs2     = (float*)(ws + OFF_RS2);
  char* xq       = ws + OFF_XQ;
  char* wqu      = ws + OFF_WQU;
  char* wqd      = ws + OFF_WQD;
  float* dqx     = (float*)(ws + OFF_DQX);
  float* dq2     = (float*)(ws + OFF_DQ2);
  float* pmax    = (float*)(ws + OFF_PMAX);
  float* wpart   = (float*)(ws + OFF_WPART);
  float* wsc     = (float*)(ws + OFF_WSC);

  k_wabs<<<2048, 256, 0, stream>>>(wu, wd, wpart);
  k_wscale<<<2, 256, 0, stream>>>(wpart, wsc);
  k_wquant<<<8192, 256, 0, stream>>>(wu, wd, wqu, wqd, wsc);
  k_rmsnorm_quant<<<M_TOK, 256, 0, stream>>>(x, nw, xq, dqx);
  k_gemm1<<<dim3(M_TOK / 256, F_DIM / 256), 512, 0, stream>>>(xq, wqu, wsc, dqx, h2, pmax);
  k_rowscale<<<M_TOK / 256, 256, 0, stream>>>(pmax, dq2, rs2);
  k_gemm2<<<dim3(M_TOK / 256, H_DIM / 256), 512, 0, stream>>>(h2, wqd, wsc, dq2, rs2, x, out);
}